// Round 2
// baseline (418.323 us; speedup 1.0000x reference)
//
#include <hip/hip_runtime.h>

#define HID 512
#define BATCH 2048

typedef float f32x4 __attribute__((ext_vector_type(4)));

// ---------------- input projection: h = [V,t] @ ip_w.T + ip_b ----------------
__global__ void k_h0(const float* __restrict__ V, const float* __restrict__ t,
                     const float* __restrict__ ipw, const float* __restrict__ ipb,
                     float* __restrict__ h) {
    int idx = blockIdx.x * blockDim.x + threadIdx.x;   // [B*HID]
    int b = idx >> 9, j = idx & 511;
    h[idx] = ipw[2 * j] * V[b] + ipw[2 * j + 1] * t[b] + ipb[j];
}

// ---------------- fp32 GEMM: C[m][n] = sum_k A[m][k] * Wseg(n)[rowseg(n)][k] + bias(n)
// N = 1536 split into 3 segments of 512 columns, each with its own W/bias pointer.
// C is [2048][1536]. A is [2048][512]. Each W segment is [512][512] row-major.
#define BM 64
#define BN 128
#define BK 32
#define PA 96    // as row: pos = (k & ~7) + m   (k-group swizzle, <=2-way banks)
#define PB 140   // bs row: pos = n + (n>>5)*4   (gap swizzle, <=2-way banks)

__global__ __launch_bounds__(256) void k_gemm(
    const float* __restrict__ A,
    const float* __restrict__ W0, const float* __restrict__ W1, const float* __restrict__ W2,
    const float* __restrict__ b0p, const float* __restrict__ b1p, const float* __restrict__ b2p,
    float* __restrict__ C)
{
    __shared__ float as[2][BK][PA];   // 24576 B
    __shared__ float bs[2][BK][PB];   // 35840 B
    const int tid = threadIdx.x;
    const int m0 = blockIdx.y * BM;
    const int n0 = blockIdx.x * BN;
    const int seg = n0 >> 9;
    const float* Wp = (seg == 0 ? W0 : (seg == 1 ? W1 : W2)) + (size_t)(n0 & 511) * HID;
    const float* bp = (seg == 0 ? b0p : (seg == 1 ? b1p : b2p)) + (n0 & 511);

    // staging mapping
    const int ar = tid >> 2, ak = (tid & 3) << 3;      // A: row 0..63, k-off {0,8,16,24}
    const int br = tid >> 1, bk = (tid & 1) << 4;      // W: row 0..127, k-off {0,16}
    const float* Aptr = A + (size_t)(m0 + ar) * HID + ak;
    const float* Wptr = Wp + (size_t)br * HID + bk;
    const int apos = ak + ar;                          // (k&~7)+m with k-group = ak
    const int bpos = br + ((br >> 5) << 2);

    // compute mapping: 4 rows x 8 cols per thread
    const int ty = tid >> 4, tx = tid & 15;
    const int bread = (tx << 3) + ((tx >> 2) << 2);

    // prologue: stage k-block 0 into buffer 0
    {
        f32x4 a0 = *(const f32x4*)Aptr, a1 = *(const f32x4*)(Aptr + 4);
        f32x4 w0 = *(const f32x4*)Wptr,      w1 = *(const f32x4*)(Wptr + 4),
              w2 = *(const f32x4*)(Wptr + 8), w3 = *(const f32x4*)(Wptr + 12);
#pragma unroll
        for (int j = 0; j < 4; ++j) as[0][ak + j][apos]      = a0[j];
#pragma unroll
        for (int j = 0; j < 4; ++j) as[0][ak + 4 + j][apos]  = a1[j];
#pragma unroll
        for (int j = 0; j < 4; ++j) bs[0][bk + j][bpos]      = w0[j];
#pragma unroll
        for (int j = 0; j < 4; ++j) bs[0][bk + 4 + j][bpos]  = w1[j];
#pragma unroll
        for (int j = 0; j < 4; ++j) bs[0][bk + 8 + j][bpos]  = w2[j];
#pragma unroll
        for (int j = 0; j < 4; ++j) bs[0][bk + 12 + j][bpos] = w3[j];
    }
    __syncthreads();

    float acc[4][8] = {};
    for (int t = 0; t < 16; ++t) {
        const int cur = t & 1;
        f32x4 a0, a1, w0, w1, w2, w3;
        if (t < 15) {   // issue next-tile global loads early (latency hides under FMAs)
            const float* Ap2 = Aptr + (t + 1) * BK;
            const float* Wp2 = Wptr + (t + 1) * BK;
            a0 = *(const f32x4*)Ap2;       a1 = *(const f32x4*)(Ap2 + 4);
            w0 = *(const f32x4*)Wp2;       w1 = *(const f32x4*)(Wp2 + 4);
            w2 = *(const f32x4*)(Wp2 + 8); w3 = *(const f32x4*)(Wp2 + 12);
        }
#pragma unroll
        for (int k = 0; k < BK; ++k) {
            f32x4 av  = *(const f32x4*)&as[cur][k][(k & ~7) + (ty << 2)];
            f32x4 bv0 = *(const f32x4*)&bs[cur][k][bread];
            f32x4 bv1 = *(const f32x4*)&bs[cur][k][bread + 4];
#pragma unroll
            for (int i = 0; i < 4; ++i)
#pragma unroll
                for (int j = 0; j < 4; ++j) {
                    acc[i][j]     += av[i] * bv0[j];
                    acc[i][j + 4] += av[i] * bv1[j];
                }
        }
        if (t < 15) {   // write-late into the other buffer, one barrier per step
            const int nxt = cur ^ 1;
#pragma unroll
            for (int j = 0; j < 4; ++j) as[nxt][ak + j][apos]      = a0[j];
#pragma unroll
            for (int j = 0; j < 4; ++j) as[nxt][ak + 4 + j][apos]  = a1[j];
#pragma unroll
            for (int j = 0; j < 4; ++j) bs[nxt][bk + j][bpos]      = w0[j];
#pragma unroll
            for (int j = 0; j < 4; ++j) bs[nxt][bk + 4 + j][bpos]  = w1[j];
#pragma unroll
            for (int j = 0; j < 4; ++j) bs[nxt][bk + 8 + j][bpos]  = w2[j];
#pragma unroll
            for (int j = 0; j < 4; ++j) bs[nxt][bk + 12 + j][bpos] = w3[j];
            __syncthreads();
        }
    }

    f32x4 bia0 = *(const f32x4*)(bp + (tx << 3));
    f32x4 bia1 = *(const f32x4*)(bp + (tx << 3) + 4);
#pragma unroll
    for (int i = 0; i < 4; ++i) {
        int row = m0 + (ty << 2) + i;
        f32x4 o0, o1;
#pragma unroll
        for (int j = 0; j < 4; ++j) { o0[j] = acc[i][j] + bia0[j]; o1[j] = acc[i][j + 4] + bia1[j]; }
        float* cp = C + (size_t)row * 1536 + n0 + (tx << 3);
        *(f32x4*)cp       = o0;
        *(f32x4*)(cp + 4) = o1;
    }
}

// ---------------- sLSTM activation (zero state): h = sigm(o)*tanh(exp(i)*tanh(g))
// g: [B][1536], cols 0-511 = i, 512-1023 = g, 1024-1535 = o
__global__ void k_slstm_act(const float* __restrict__ g, float* __restrict__ h) {
    int idx = blockIdx.x * blockDim.x + threadIdx.x;
    int b = idx >> 9, j = idx & 511;
    const float* gr = g + (size_t)b * 1536;
    float gi = gr[j], gg = gr[512 + j], go = gr[1024 + j];
    float c = expf(gi) * tanhf(gg);
    h[idx] = tanhf(c) / (1.f + expf(-go));
}

// ---------------- mLSTM head math + layernorm (zero initial state) ----------------
// qkv: [B][1536], cols 0-511 = q, 512-1023 = k, 1024-1535 = v
__global__ __launch_bounds__(512) void k_mlstm(
    const float* __restrict__ qkv, const float* __restrict__ hin,
    const float* __restrict__ igw, const float* __restrict__ igb,
    const float* __restrict__ lng, const float* __restrict__ lnb,
    float* __restrict__ hout)
{
    int b = blockIdx.x;
    int tid = threadIdx.x, head = tid >> 6, lane = tid & 63;

    // input gate: i = exp(igw[head] . hin[b] + igb[head])
    const float* hrow = hin + (size_t)b * HID;
    const float* wrow = igw + head * HID;
    float s = 0.f;
#pragma unroll
    for (int k = 0; k < 8; ++k)
        s += wrow[lane + 64 * k] * hrow[lane + 64 * k];
#pragma unroll
    for (int off = 32; off; off >>= 1) s += __shfl_xor(s, off);
    float ig = expf(s + igb[head]);

    const float* qr = qkv + (size_t)b * 1536;
    float q = qr[tid], kk = qr[512 + tid], v = qr[1024 + tid];
    float kq = kk * q, vq = v * q;
#pragma unroll
    for (int off = 32; off; off >>= 1) { kq += __shfl_xor(kq, off); vq += __shfl_xor(vq, off); }
    float den = ig * (vq + 1.0f) + 1e-6f;
    float hv  = v * (ig * kq) / den;

    // layernorm over 512
    __shared__ float red[16];
    float s1 = hv, s2 = hv * hv;
#pragma unroll
    for (int off = 32; off; off >>= 1) { s1 += __shfl_xor(s1, off); s2 += __shfl_xor(s2, off); }
    if (lane == 0) { red[head] = s1; red[8 + head] = s2; }
    __syncthreads();
    float t1 = 0.f, t2 = 0.f;
#pragma unroll
    for (int h2 = 0; h2 < 8; ++h2) { t1 += red[h2]; t2 += red[8 + h2]; }
    float mu  = t1 * (1.f / 512.f);
    float var = t2 * (1.f / 512.f) - mu * mu;
    float o = (hv - mu) * rsqrtf(var + 1e-5f) * lng[tid] + lnb[tid];
    hout[(size_t)b * HID + tid] = o;
}

// ---------------- final projection: out[b] = h[b] . op_w + op_b ----------------
__global__ void k_out(const float* __restrict__ h, const float* __restrict__ opw,
                      const float* __restrict__ opb, float* __restrict__ out) {
    int b = blockIdx.x * 4 + (threadIdx.x >> 6);
    int lane = threadIdx.x & 63;
    float s = 0.f;
#pragma unroll
    for (int k = 0; k < 8; ++k)
        s += h[(size_t)b * HID + lane + 64 * k] * opw[lane + 64 * k];
#pragma unroll
    for (int off = 32; off; off >>= 1) s += __shfl_xor(s, off);
    if (lane == 0) out[b] = s + opb[0];
}

extern "C" void kernel_launch(void* const* d_in, const int* in_sizes, int n_in,
                              void* d_out, int out_size, void* d_ws, size_t ws_size,
                              hipStream_t stream) {
    const float* V    = (const float*)d_in[0];
    const float* t    = (const float*)d_in[1];
    const float* ip_w = (const float*)d_in[2];
    const float* ip_b = (const float*)d_in[3];
    const float* op_w = (const float*)d_in[4];
    const float* op_b = (const float*)d_in[5];
    const float* s0_W = (const float*)d_in[6];
    const float* s0_b = (const float*)d_in[7];
    const float* s2_W = (const float*)d_in[9];
    const float* s2_b = (const float*)d_in[10];
    const float* m1_Wq = (const float*)d_in[12];
    const float* m1_Wk = (const float*)d_in[13];
    const float* m1_Wv = (const float*)d_in[14];
    const float* m1_bq = (const float*)d_in[15];
    const float* m1_bk = (const float*)d_in[16];
    const float* m1_bv = (const float*)d_in[17];
    const float* m1_igw = (const float*)d_in[18];
    const float* m1_igb = (const float*)d_in[19];
    const float* m1_lng = (const float*)d_in[22];
    const float* m1_lnb = (const float*)d_in[23];
    const float* m3_Wq = (const float*)d_in[24];
    const float* m3_Wk = (const float*)d_in[25];
    const float* m3_Wv = (const float*)d_in[26];
    const float* m3_bq = (const float*)d_in[27];
    const float* m3_bk = (const float*)d_in[28];
    const float* m3_bv = (const float*)d_in[29];
    const float* m3_igw = (const float*)d_in[30];
    const float* m3_igb = (const float*)d_in[31];
    const float* m3_lng = (const float*)d_in[34];
    const float* m3_lnb = (const float*)d_in[35];

    char* ws = (char*)d_ws;
    float* hA = (float*)ws;                        // 4 MB
    float* hB = (float*)(ws + ((size_t)4 << 20));  // 4 MB
    float* gq = (float*)(ws + ((size_t)8 << 20));  // 12 MB

    dim3 gg(12, 32);

    k_h0<<<4096, 256, 0, stream>>>(V, t, ip_w, ip_b, hA);

    // layer 0: sLSTM  (cols: i = W rows 0-511, g = rows 1024-1535, o = rows 1536-2047)
    k_gemm<<<gg, 256, 0, stream>>>(hA, s0_W, s0_W + 1024 * 512, s0_W + 1536 * 512,
                                   s0_b, s0_b + 1024, s0_b + 1536, gq);
    k_slstm_act<<<4096, 256, 0, stream>>>(gq, hB);
    // layer 1: mLSTM (fused q|k|v)
    k_gemm<<<gg, 256, 0, stream>>>(hB, m1_Wq, m1_Wk, m1_Wv, m1_bq, m1_bk, m1_bv, gq);
    k_mlstm<<<BATCH, 512, 0, stream>>>(gq, hB, m1_igw, m1_igb, m1_lng, m1_lnb, hA);
    // layer 2: sLSTM
    k_gemm<<<gg, 256, 0, stream>>>(hA, s2_W, s2_W + 1024 * 512, s2_W + 1536 * 512,
                                   s2_b, s2_b + 1024, s2_b + 1536, gq);
    k_slstm_act<<<4096, 256, 0, stream>>>(gq, hB);
    // layer 3: mLSTM
    k_gemm<<<gg, 256, 0, stream>>>(hB, m3_Wq, m3_Wk, m3_Wv, m3_bq, m3_bk, m3_bv, gq);
    k_mlstm<<<BATCH, 512, 0, stream>>>(gq, hB, m3_igw, m3_igb, m3_lng, m3_lnb, hA);

    k_out<<<512, 256, 0, stream>>>(hA, op_w, op_b, (float*)d_out);
}

// Round 3
// 228.307 us; speedup vs baseline: 1.8323x; 1.8323x over previous
//
#include <hip/hip_runtime.h>
#include <hip/hip_bf16.h>

#define HID 512
#define BATCH 2048

typedef __bf16 bf16x8 __attribute__((ext_vector_type(8)));
typedef float f32x4 __attribute__((ext_vector_type(4)));
typedef __hip_bfloat16 bf16;

__device__ inline void split_store(float x, bf16* __restrict__ hi, bf16* __restrict__ lo, size_t idx) {
    bf16 h = __float2bfloat16(x);
    hi[idx] = h;
    lo[idx] = __float2bfloat16(x - __bfloat162float(h));
}

// ---------------- weight fp32 -> hi/lo bf16 split ----------------
// segments: s0_W (1M), s2_W (1M), m1_Wq/Wk/Wv, m3_Wq/Wk/Wv (6 x 256K)
struct CvtArgs { const float* src[8]; };

__global__ void k_cvt(CvtArgs a, bf16* __restrict__ hi, bf16* __restrict__ lo, int total) {
    int idx = blockIdx.x * blockDim.x + threadIdx.x;
    if (idx >= total) return;
    int seg, off;
    if (idx < 2097152) { seg = idx >> 20; off = idx & 1048575; }
    else { int r = idx - 2097152; seg = 2 + (r >> 18); off = r & 262143; }
    float w = a.src[seg][off];
    bf16 h = __float2bfloat16(w);
    hi[idx] = h;
    lo[idx] = __float2bfloat16(w - __bfloat162float(h));
}

// ---------------- input projection: h = [V,t] @ ip_w.T + ip_b ----------------
__global__ void k_h0(const float* __restrict__ V, const float* __restrict__ t,
                     const float* __restrict__ ipw, const float* __restrict__ ipb,
                     bf16* __restrict__ hhi, bf16* __restrict__ hlo) {
    int idx = blockIdx.x * blockDim.x + threadIdx.x;   // [B*HID]
    int b = idx >> 9, j = idx & 511;
    float x = ipw[2 * j] * V[b] + ipw[2 * j + 1] * t[b] + ipb[j];
    split_store(x, hhi, hlo, idx);
}

// ---------------- split-bf16 MFMA GEMM ----------------
// C[m][n] = sum_k A[m][k] * Wseg(n)[n&511][k] + bias(n),  A=[2048][512], N=1536 (3 segs of 512)
// A,W given as hi/lo bf16 pairs; C = Ah*Wh + Al*Wh + Ah*Wl (fp32 accum).
__global__ __launch_bounds__(256, 3) void k_gemm(
    const bf16* __restrict__ Ahi, const bf16* __restrict__ Alo,
    const bf16* __restrict__ Wh0, const bf16* __restrict__ Wh1, const bf16* __restrict__ Wh2,
    const bf16* __restrict__ Wl0, const bf16* __restrict__ Wl1, const bf16* __restrict__ Wl2,
    const float* __restrict__ b0, const float* __restrict__ b1, const float* __restrict__ b2,
    float* __restrict__ C)
{
    const int tid  = threadIdx.x;
    const int wave = tid >> 6, lane = tid & 63;
    const int m0 = blockIdx.y * 32;                 // 32-row block tile
    const int nw = blockIdx.x * 128 + wave * 32;    // 32-col wave tile
    const int lr = lane & 15, lk = (lane >> 4) * 8;

    const bf16* aH[2]; const bf16* aL[2];
#pragma unroll
    for (int i = 0; i < 2; ++i) {
        size_t off = (size_t)(m0 + i * 16 + lr) * HID + lk;
        aH[i] = Ahi + off; aL[i] = Alo + off;
    }
    const bf16* bH[2]; const bf16* bL[2]; float biasv[2];
#pragma unroll
    for (int j = 0; j < 2; ++j) {
        int cb  = nw + j * 16;
        int seg = cb >> 9;
        const bf16* wh = seg == 0 ? Wh0 : (seg == 1 ? Wh1 : Wh2);
        const bf16* wl = seg == 0 ? Wl0 : (seg == 1 ? Wl1 : Wl2);
        const float* bp = seg == 0 ? b0 : (seg == 1 ? b1 : b2);
        size_t off = (size_t)((cb & 511) + lr) * HID + lk;
        bH[j] = wh + off; bL[j] = wl + off;
        biasv[j] = bp[(cb & 511) + lr];
    }

    f32x4 acc[2][2] = {};
#pragma unroll 4
    for (int k0 = 0; k0 < HID; k0 += 32) {
        bf16x8 ah[2], al[2], bh[2], bl[2];
#pragma unroll
        for (int i = 0; i < 2; ++i) {
            ah[i] = *reinterpret_cast<const bf16x8*>(aH[i] + k0);
            al[i] = *reinterpret_cast<const bf16x8*>(aL[i] + k0);
        }
#pragma unroll
        for (int j = 0; j < 2; ++j) {
            bh[j] = *reinterpret_cast<const bf16x8*>(bH[j] + k0);
            bl[j] = *reinterpret_cast<const bf16x8*>(bL[j] + k0);
        }
#pragma unroll
        for (int i = 0; i < 2; ++i)
#pragma unroll
            for (int j = 0; j < 2; ++j) {
                acc[i][j] = __builtin_amdgcn_mfma_f32_16x16x32_bf16(ah[i], bh[j], acc[i][j], 0, 0, 0);
                acc[i][j] = __builtin_amdgcn_mfma_f32_16x16x32_bf16(al[i], bh[j], acc[i][j], 0, 0, 0);
                acc[i][j] = __builtin_amdgcn_mfma_f32_16x16x32_bf16(ah[i], bl[j], acc[i][j], 0, 0, 0);
            }
    }

    const int rb = (lane >> 4) * 4;   // D: col = lane&15, row = (lane>>4)*4 + r
#pragma unroll
    for (int i = 0; i < 2; ++i)
#pragma unroll
        for (int j = 0; j < 2; ++j) {
            int col = nw + j * 16 + lr;
#pragma unroll
            for (int r = 0; r < 4; ++r) {
                int row = m0 + i * 16 + rb + r;
                C[(size_t)row * 1536 + col] = acc[i][j][r] + biasv[j];
            }
        }
}

// ---------------- sLSTM activation (zero state): h = sigm(o)*tanh(exp(i)*tanh(g))
__global__ void k_slstm_act(const float* __restrict__ g, bf16* __restrict__ hhi, bf16* __restrict__ hlo) {
    int idx = blockIdx.x * blockDim.x + threadIdx.x;
    int b = idx >> 9, j = idx & 511;
    const float* gr = g + (size_t)b * 1536;
    float gi = gr[j], gg = gr[512 + j], go = gr[1024 + j];
    float c = expf(gi) * tanhf(gg);
    float hv = tanhf(c) / (1.f + expf(-go));
    split_store(hv, hhi, hlo, idx);
}

// ---------------- mLSTM head math + layernorm (zero initial state) ----------------
// qkv: [B][1536] fp32, cols 0-511 = q, 512-1023 = k, 1024-1535 = v
__global__ __launch_bounds__(512) void k_mlstm(
    const float* __restrict__ qkv,
    const bf16* __restrict__ hinh, const bf16* __restrict__ hinl,
    const float* __restrict__ igw, const float* __restrict__ igb,
    const float* __restrict__ lng, const float* __restrict__ lnb,
    bf16* __restrict__ outh, bf16* __restrict__ outl)
{
    int b = blockIdx.x;
    int tid = threadIdx.x, head = tid >> 6, lane = tid & 63;

    // input gate: i = exp(igw[head] . hin[b] + igb[head])
    const bf16*  hh = hinh + (size_t)b * HID;
    const bf16*  hl = hinl + (size_t)b * HID;
    const float* wrow = igw + head * HID;
    float s = 0.f;
#pragma unroll
    for (int k = 0; k < 8; ++k) {
        int p = lane + 64 * k;
        s += wrow[p] * (__bfloat162float(hh[p]) + __bfloat162float(hl[p]));
    }
#pragma unroll
    for (int off = 32; off; off >>= 1) s += __shfl_xor(s, off);
    float ig = expf(s + igb[head]);

    const float* qr = qkv + (size_t)b * 1536;
    float q = qr[tid], kk = qr[512 + tid], v = qr[1024 + tid];
    float kq = kk * q, vq = v * q;
#pragma unroll
    for (int off = 32; off; off >>= 1) { kq += __shfl_xor(kq, off); vq += __shfl_xor(vq, off); }
    float den = ig * (vq + 1.0f) + 1e-6f;
    float hv  = v * (ig * kq) / den;

    // layernorm over 512
    __shared__ float red[16];
    float s1 = hv, s2 = hv * hv;
#pragma unroll
    for (int off = 32; off; off >>= 1) { s1 += __shfl_xor(s1, off); s2 += __shfl_xor(s2, off); }
    if (lane == 0) { red[head] = s1; red[8 + head] = s2; }
    __syncthreads();
    float t1 = 0.f, t2 = 0.f;
#pragma unroll
    for (int h2 = 0; h2 < 8; ++h2) { t1 += red[h2]; t2 += red[8 + h2]; }
    float mu  = t1 * (1.f / 512.f);
    float var = t2 * (1.f / 512.f) - mu * mu;
    float o = (hv - mu) * rsqrtf(var + 1e-5f) * lng[tid] + lnb[tid];
    split_store(o, outh, outl, (size_t)b * HID + tid);
}

// ---------------- final projection: out[b] = h[b] . op_w + op_b ----------------
__global__ void k_out(const bf16* __restrict__ hh, const bf16* __restrict__ hl,
                      const float* __restrict__ opw,
                      const float* __restrict__ opb, float* __restrict__ out) {
    int b = blockIdx.x * 4 + (threadIdx.x >> 6);
    int lane = threadIdx.x & 63;
    float s = 0.f;
#pragma unroll
    for (int k = 0; k < 8; ++k) {
        size_t p = (size_t)b * HID + lane + 64 * k;
        s += (__bfloat162float(hh[p]) + __bfloat162float(hl[p])) * opw[lane + 64 * k];
    }
#pragma unroll
    for (int off = 32; off; off >>= 1) s += __shfl_xor(s, off);
    if (lane == 0) out[b] = s + opb[0];
}

extern "C" void kernel_launch(void* const* d_in, const int* in_sizes, int n_in,
                              void* d_out, int out_size, void* d_ws, size_t ws_size,
                              hipStream_t stream) {
    const float* V    = (const float*)d_in[0];
    const float* t    = (const float*)d_in[1];
    const float* ip_w = (const float*)d_in[2];
    const float* ip_b = (const float*)d_in[3];
    const float* op_w = (const float*)d_in[4];
    const float* op_b = (const float*)d_in[5];
    const float* s0_W = (const float*)d_in[6];
    const float* s0_b = (const float*)d_in[7];
    const float* s2_W = (const float*)d_in[9];
    const float* s2_b = (const float*)d_in[10];
    const float* m1_Wq = (const float*)d_in[12];
    const float* m1_Wk = (const float*)d_in[13];
    const float* m1_Wv = (const float*)d_in[14];
    const float* m1_bq = (const float*)d_in[15];
    const float* m1_bk = (const float*)d_in[16];
    const float* m1_bv = (const float*)d_in[17];
    const float* m1_igw = (const float*)d_in[18];
    const float* m1_igb = (const float*)d_in[19];
    const float* m1_lng = (const float*)d_in[22];
    const float* m1_lnb = (const float*)d_in[23];
    const float* m3_Wq = (const float*)d_in[24];
    const float* m3_Wk = (const float*)d_in[25];
    const float* m3_Wv = (const float*)d_in[26];
    const float* m3_bq = (const float*)d_in[27];
    const float* m3_bk = (const float*)d_in[28];
    const float* m3_bv = (const float*)d_in[29];
    const float* m3_igw = (const float*)d_in[30];
    const float* m3_igb = (const float*)d_in[31];
    const float* m3_lng = (const float*)d_in[34];
    const float* m3_lnb = (const float*)d_in[35];

    char* ws = (char*)d_ws;
    bf16* whi  = (bf16*)ws;                            // 3,670,016 elems = 7,340,032 B
    bf16* wlo  = (bf16*)(ws + 7340032);
    bf16* hAhi = (bf16*)(ws + 14680064);               // [B][HID] each 2 MB
    bf16* hAlo = (bf16*)(ws + 16777216);
    bf16* hBhi = (bf16*)(ws + 18874368);
    bf16* hBlo = (bf16*)(ws + 20971520);
    float* gq  = (float*)(ws + 23068672);              // [B][1536] f32, 12 MB

    // weight segment bases (elements)
    const size_t s0_o = 0, s2_o = 1048576;
    const size_t q1_o = 2097152, k1_o = 2359296, v1_o = 2621440;
    const size_t q3_o = 2883584, k3_o = 3145728, v3_o = 3407872;

    CvtArgs ca;
    ca.src[0] = s0_W; ca.src[1] = s2_W;
    ca.src[2] = m1_Wq; ca.src[3] = m1_Wk; ca.src[4] = m1_Wv;
    ca.src[5] = m3_Wq; ca.src[6] = m3_Wk; ca.src[7] = m3_Wv;
    k_cvt<<<14336, 256, 0, stream>>>(ca, whi, wlo, 3670016);

    k_h0<<<4096, 256, 0, stream>>>(V, t, ip_w, ip_b, hAhi, hAlo);

    dim3 gg(12, 64);   // N/128 x M/32 = 768 blocks = 3/CU

    // layer 0: sLSTM (segments i = rows 0-511, g = rows 1024-1535, o = rows 1536-2047)
    k_gemm<<<gg, 256, 0, stream>>>(hAhi, hAlo,
        whi + s0_o, whi + s0_o + 524288, whi + s0_o + 786432,
        wlo + s0_o, wlo + s0_o + 524288, wlo + s0_o + 786432,
        s0_b, s0_b + 1024, s0_b + 1536, gq);
    k_slstm_act<<<4096, 256, 0, stream>>>(gq, hBhi, hBlo);
    // layer 1: mLSTM (fused q|k|v)
    k_gemm<<<gg, 256, 0, stream>>>(hBhi, hBlo,
        whi + q1_o, whi + k1_o, whi + v1_o,
        wlo + q1_o, wlo + k1_o, wlo + v1_o,
        m1_bq, m1_bk, m1_bv, gq);
    k_mlstm<<<BATCH, 512, 0, stream>>>(gq, hBhi, hBlo, m1_igw, m1_igb, m1_lng, m1_lnb, hAhi, hAlo);
    // layer 2: sLSTM
    k_gemm<<<gg, 256, 0, stream>>>(hAhi, hAlo,
        whi + s2_o, whi + s2_o + 524288, whi + s2_o + 786432,
        wlo + s2_o, wlo + s2_o + 524288, wlo + s2_o + 786432,
        s2_b, s2_b + 1024, s2_b + 1536, gq);
    k_slstm_act<<<4096, 256, 0, stream>>>(gq, hBhi, hBlo);
    // layer 3: mLSTM
    k_gemm<<<gg, 256, 0, stream>>>(hBhi, hBlo,
        whi + q3_o, whi + k3_o, whi + v3_o,
        wlo + q3_o, wlo + k3_o, wlo + v3_o,
        m3_bq, m3_bk, m3_bv, gq);
    k_mlstm<<<BATCH, 512, 0, stream>>>(gq, hBhi, hBlo, m3_igw, m3_igb, m3_lng, m3_lnb, hAhi, hAlo);

    k_out<<<512, 256, 0, stream>>>(hAhi, hAlo, op_w, op_b, (float*)d_out);
}

// Round 4
// 185.465 us; speedup vs baseline: 2.2555x; 1.2310x over previous
//
#include <hip/hip_runtime.h>
#include <hip/hip_bf16.h>

#define HID 512
#define BATCH 2048

typedef __bf16 bf16x8 __attribute__((ext_vector_type(8)));
typedef float f32x4 __attribute__((ext_vector_type(4)));
typedef float f32x16 __attribute__((ext_vector_type(16)));
typedef __hip_bfloat16 bf16;

__device__ inline unsigned short f2bf(float x) {
    bf16 h = __float2bfloat16(x);
    return __builtin_bit_cast(unsigned short, h);
}

__device__ inline void gload16(const void* g, void* l) {
    __builtin_amdgcn_global_load_lds((const __attribute__((address_space(1))) void*)g,
                                     (__attribute__((address_space(3))) void*)l, 16, 0, 0);
}

// ---------------- weight fp32 -> hi/lo bf16 split (x4 vectorized) ----------------
struct CvtArgs { const float* src[8]; };

__global__ void k_cvt(CvtArgs a, unsigned short* __restrict__ hi, unsigned short* __restrict__ lo) {
    int idx4 = (blockIdx.x * blockDim.x + threadIdx.x) << 2;   // total 3,670,016
    int seg, off;
    if (idx4 < 2097152) { seg = idx4 >> 20; off = idx4 & 1048575; }
    else { int r = idx4 - 2097152; seg = 2 + (r >> 18); off = r & 262143; }
    f32x4 w = *(const f32x4*)(a.src[seg] + off);
    ushort4 h, l;
    h.x = f2bf(w[0]); h.y = f2bf(w[1]); h.z = f2bf(w[2]); h.w = f2bf(w[3]);
    l.x = f2bf(w[0] - __bfloat162float(__builtin_bit_cast(bf16, h.x)));
    l.y = f2bf(w[1] - __bfloat162float(__builtin_bit_cast(bf16, h.y)));
    l.z = f2bf(w[2] - __bfloat162float(__builtin_bit_cast(bf16, h.z)));
    l.w = f2bf(w[3] - __bfloat162float(__builtin_bit_cast(bf16, h.w)));
    *(ushort4*)(hi + idx4) = h;
    *(ushort4*)(lo + idx4) = l;
}

// ---------------- input projection: h = [V,t] @ ip_w.T + ip_b (x4) ----------------
__global__ void k_h0(const float* __restrict__ V, const float* __restrict__ t,
                     const float* __restrict__ ipw, const float* __restrict__ ipb,
                     unsigned short* __restrict__ hhi, unsigned short* __restrict__ hlo) {
    int idx = blockIdx.x * blockDim.x + threadIdx.x;   // B*HID/4
    int b = idx >> 7, j4 = (idx & 127) << 2;
    float vv = V[b], tt = t[b];
    f32x4 w0 = *(const f32x4*)(ipw + 2 * j4);
    f32x4 w1 = *(const f32x4*)(ipw + 2 * j4 + 4);
    f32x4 bb = *(const f32x4*)(ipb + j4);
    float x[4] = { w0[0] * vv + w0[1] * tt + bb[0], w0[2] * vv + w0[3] * tt + bb[1],
                   w1[0] * vv + w1[1] * tt + bb[2], w1[2] * vv + w1[3] * tt + bb[3] };
    ushort4 h, l;
    h.x = f2bf(x[0]); h.y = f2bf(x[1]); h.z = f2bf(x[2]); h.w = f2bf(x[3]);
    l.x = f2bf(x[0] - __bfloat162float(__builtin_bit_cast(bf16, h.x)));
    l.y = f2bf(x[1] - __bfloat162float(__builtin_bit_cast(bf16, h.y)));
    l.z = f2bf(x[2] - __bfloat162float(__builtin_bit_cast(bf16, h.z)));
    l.w = f2bf(x[3] - __bfloat162float(__builtin_bit_cast(bf16, h.w)));
    size_t o = (size_t)b * HID + j4;
    *(ushort4*)(hhi + o) = h;
    *(ushort4*)(hlo + o) = l;
}

// ---------------- split-bf16 GEMM as ext-K bf16 GEMM ----------------
// C[2048][1536] = A'[2048][1536ext] * W'[1536][1536ext]^T + bias
// ext-K segs (512 each): A' = {Ahi, Alo, Ahi};  W' = {Wh, Wh, Wl}.
// N segs (512 each) pick (Wh,Wl,bias) from 0/1/2.
// Tile 64(M)x128(N), 8 waves, wave = one 32x32 via mfma_f32_32x32x16_bf16, BK=64.
__global__ __launch_bounds__(512) void k_gemm(
    const bf16* __restrict__ Ahi, const bf16* __restrict__ Alo,
    const bf16* __restrict__ Wh0, const bf16* __restrict__ Wh1, const bf16* __restrict__ Wh2,
    const bf16* __restrict__ Wl0, const bf16* __restrict__ Wl1, const bf16* __restrict__ Wl2,
    const float* __restrict__ b0, const float* __restrict__ b1, const float* __restrict__ b2,
    float* __restrict__ C)
{
    // LDS: per buffer 24KB = A 8 chunks + B 16 chunks, chunk = 1KB (64 lanes x 16B),
    // chunk holds one MFMA fragment: lane l <- [32-row block][(l&31)], k-sub [(l>>5)*8..+8)
    __shared__ __align__(16) bf16 lds[2][12288];
    const int tid = threadIdx.x, w = tid >> 6, lane = tid & 63;

    // XCD-chunked swizzle: 384 blocks = 8 XCDs x 48
    const int bid = blockIdx.x;
    const int id2 = (bid & 7) * 48 + (bid >> 3);
    const int bxn = id2 / 32;          // n-tile 0..11
    const int bym = id2 % 32;          // m-tile 0..31
    const int m0 = bym * 64, n0 = bxn * 128;
    const int nseg = n0 >> 9, nloc = n0 & 511;
    const bf16* Wh = nseg == 0 ? Wh0 : (nseg == 1 ? Wh1 : Wh2);
    const bf16* Wl = nseg == 0 ? Wl0 : (nseg == 1 ? Wl1 : Wl2);
    const float* bp = nseg == 0 ? b0 : (nseg == 1 ? b1 : b2);

    // staging: wave w stages A-chunk w (i=w>>2, ks=w&3) and B-chunks w, w+8 (j=c>>2, ks=c&3)
    const int ks16 = (w & 3) << 4;                      // ks*16
    const int khalf = (lane >> 5) << 3;                 // (lane>>5)*8
    const size_t aoff = (size_t)(m0 + ((w >> 2) << 5) + (lane & 31)) * HID + ks16 + khalf;
    const size_t boff1 = (size_t)(nloc + ((w >> 2) << 5) + (lane & 31)) * HID + ks16 + khalf;
    const size_t boff2 = boff1 + (size_t)64 * HID;      // j += 2  -> +64 rows
    bf16* const adst  = &lds[0][0] + (w << 9) + (lane << 3);
    bf16* const bdst1 = &lds[0][0] + 4096 + (w << 9) + (lane << 3);
    bf16* const bdst2 = bdst1 + (8 << 9);
    const int lbuf = 12288;                             // elems per buffer

    // compute: wave (wm=w>>2, wn=w&3); A chunk wm*4+ks, B chunk wn*4+ks
    const int ard = ((w >> 2) << 11) + (lane << 3);           // + ks*512
    const int brd = 4096 + ((w & 3) << 11) + (lane << 3);

    f32x16 acc = {0,0,0,0,0,0,0,0,0,0,0,0,0,0,0,0};

    auto STAGE = [&](int t, int bb) {
        const int seg = t >> 3;
        const int kl = (t & 7) << 6;
        const bf16* ab = (seg == 1 ? Alo : Ahi);
        const bf16* wb = (seg == 2 ? Wl : Wh);
        gload16(ab + aoff + kl, adst + bb * lbuf);
        gload16(wb + boff1 + kl, bdst1 + bb * lbuf);
        gload16(wb + boff2 + kl, bdst2 + bb * lbuf);
    };

    STAGE(0, 0);
    __syncthreads();
    for (int t = 0; t < 24; ++t) {
        const int cur = t & 1;
        if (t < 23) STAGE(t + 1, cur ^ 1);
        const bf16* lb = &lds[cur][0];
#pragma unroll
        for (int ks = 0; ks < 4; ++ks) {
            bf16x8 af = *(const bf16x8*)(lb + ard + (ks << 9));
            bf16x8 bf_ = *(const bf16x8*)(lb + brd + (ks << 9));
            acc = __builtin_amdgcn_mfma_f32_32x32x16_bf16(af, bf_, acc, 0, 0, 0);
        }
        __syncthreads();
    }

    // epilogue: D layout col = lane&31, row = (r&3) + 8*(r>>2) + 4*(lane>>5)
    const int ccol = n0 + ((w & 3) << 5) + (lane & 31);
    const float bv = bp[nloc + ((w & 3) << 5) + (lane & 31)];
    const int rbase = m0 + ((w >> 2) << 5) + ((lane >> 5) << 2);
#pragma unroll
    for (int r = 0; r < 16; ++r) {
        int row = rbase + (r & 3) + ((r >> 2) << 3);
        C[(size_t)row * 1536 + ccol] = acc[r] + bv;
    }
}

// ---------------- sLSTM activation (x4): h = sigm(o)*tanh(exp(i)*tanh(g)) ----------------
__global__ void k_slstm_act(const float* __restrict__ g,
                            unsigned short* __restrict__ hhi, unsigned short* __restrict__ hlo) {
    int idx = blockIdx.x * blockDim.x + threadIdx.x;   // B*HID/4
    int b = idx >> 7, j4 = (idx & 127) << 2;
    const float* gr = g + (size_t)b * 1536 + j4;
    f32x4 gi = *(const f32x4*)gr;
    f32x4 gg = *(const f32x4*)(gr + 512);
    f32x4 go = *(const f32x4*)(gr + 1024);
    ushort4 h, l;
    float x[4];
#pragma unroll
    for (int u = 0; u < 4; ++u)
        x[u] = tanhf(expf(gi[u]) * tanhf(gg[u])) / (1.f + expf(-go[u]));
    h.x = f2bf(x[0]); h.y = f2bf(x[1]); h.z = f2bf(x[2]); h.w = f2bf(x[3]);
    l.x = f2bf(x[0] - __bfloat162float(__builtin_bit_cast(bf16, h.x)));
    l.y = f2bf(x[1] - __bfloat162float(__builtin_bit_cast(bf16, h.y)));
    l.z = f2bf(x[2] - __bfloat162float(__builtin_bit_cast(bf16, h.z)));
    l.w = f2bf(x[3] - __bfloat162float(__builtin_bit_cast(bf16, h.w)));
    size_t o = (size_t)b * HID + j4;
    *(ushort4*)(hhi + o) = h;
    *(ushort4*)(hlo + o) = l;
}

// ---------------- mLSTM head math + layernorm (zero initial state) ----------------
__global__ __launch_bounds__(512) void k_mlstm(
    const float* __restrict__ qkv,
    const bf16* __restrict__ hinh, const bf16* __restrict__ hinl,
    const float* __restrict__ igw, const float* __restrict__ igb,
    const float* __restrict__ lng, const float* __restrict__ lnb,
    unsigned short* __restrict__ outh, unsigned short* __restrict__ outl)
{
    int b = blockIdx.x;
    int tid = threadIdx.x, head = tid >> 6, lane = tid & 63;

    const bf16*  hh = hinh + (size_t)b * HID;
    const bf16*  hl = hinl + (size_t)b * HID;
    const float* wrow = igw + head * HID;
    float s = 0.f;
#pragma unroll
    for (int k = 0; k < 8; ++k) {
        int p = lane + 64 * k;
        s += wrow[p] * (__bfloat162float(hh[p]) + __bfloat162float(hl[p]));
    }
#pragma unroll
    for (int off = 32; off; off >>= 1) s += __shfl_xor(s, off);
    float ig = expf(s + igb[head]);

    const float* qr = qkv + (size_t)b * 1536;
    float q = qr[tid], kk = qr[512 + tid], v = qr[1024 + tid];
    float kq = kk * q, vq = v * q;
#pragma unroll
    for (int off = 32; off; off >>= 1) { kq += __shfl_xor(kq, off); vq += __shfl_xor(vq, off); }
    float den = ig * (vq + 1.0f) + 1e-6f;
    float hv  = v * (ig * kq) / den;

    __shared__ float red[16];
    float s1 = hv, s2 = hv * hv;
#pragma unroll
    for (int off = 32; off; off >>= 1) { s1 += __shfl_xor(s1, off); s2 += __shfl_xor(s2, off); }
    if (lane == 0) { red[head] = s1; red[8 + head] = s2; }
    __syncthreads();
    float t1 = 0.f, t2 = 0.f;
#pragma unroll
    for (int h2 = 0; h2 < 8; ++h2) { t1 += red[h2]; t2 += red[8 + h2]; }
    float mu  = t1 * (1.f / 512.f);
    float var = t2 * (1.f / 512.f) - mu * mu;
    float o = (hv - mu) * rsqrtf(var + 1e-5f) * lng[tid] + lnb[tid];
    unsigned short oh = f2bf(o);
    size_t p = (size_t)b * HID + tid;
    outh[p] = oh;
    outl[p] = f2bf(o - __bfloat162float(__builtin_bit_cast(bf16, oh)));
}

// ---------------- final projection ----------------
__global__ void k_out(const bf16* __restrict__ hh, const bf16* __restrict__ hl,
                      const float* __restrict__ opw,
                      const float* __restrict__ opb, float* __restrict__ out) {
    int b = blockIdx.x * 4 + (threadIdx.x >> 6);
    int lane = threadIdx.x & 63;
    float s = 0.f;
#pragma unroll
    for (int k = 0; k < 8; ++k) {
        size_t p = (size_t)b * HID + lane + 64 * k;
        s += (__bfloat162float(hh[p]) + __bfloat162float(hl[p])) * opw[lane + 64 * k];
    }
#pragma unroll
    for (int off = 32; off; off >>= 1) s += __shfl_xor(s, off);
    if (lane == 0) out[b] = s + opb[0];
}

extern "C" void kernel_launch(void* const* d_in, const int* in_sizes, int n_in,
                              void* d_out, int out_size, void* d_ws, size_t ws_size,
                              hipStream_t stream) {
    const float* V    = (const float*)d_in[0];
    const float* t    = (const float*)d_in[1];
    const float* ip_w = (const float*)d_in[2];
    const float* ip_b = (const float*)d_in[3];
    const float* op_w = (const float*)d_in[4];
    const float* op_b = (const float*)d_in[5];
    const float* s0_W = (const float*)d_in[6];
    const float* s0_b = (const float*)d_in[7];
    const float* s2_W = (const float*)d_in[9];
    const float* s2_b = (const float*)d_in[10];
    const float* m1_Wq = (const float*)d_in[12];
    const float* m1_Wk = (const float*)d_in[13];
    const float* m1_Wv = (const float*)d_in[14];
    const float* m1_bq = (const float*)d_in[15];
    const float* m1_bk = (const float*)d_in[16];
    const float* m1_bv = (const float*)d_in[17];
    const float* m1_igw = (const float*)d_in[18];
    const float* m1_igb = (const float*)d_in[19];
    const float* m1_lng = (const float*)d_in[22];
    const float* m1_lnb = (const float*)d_in[23];
    const float* m3_Wq = (const float*)d_in[24];
    const float* m3_Wk = (const float*)d_in[25];
    const float* m3_Wv = (const float*)d_in[26];
    const float* m3_bq = (const float*)d_in[27];
    const float* m3_bk = (const float*)d_in[28];
    const float* m3_bv = (const float*)d_in[29];
    const float* m3_igw = (const float*)d_in[30];
    const float* m3_igb = (const float*)d_in[31];
    const float* m3_lng = (const float*)d_in[34];
    const float* m3_lnb = (const float*)d_in[35];

    char* ws = (char*)d_ws;
    bf16* whi  = (bf16*)ws;                            // 3,670,016 elems
    bf16* wlo  = (bf16*)(ws + 7340032);
    bf16* hAhi = (bf16*)(ws + 14680064);               // [B][HID] each 2 MB
    bf16* hAlo = (bf16*)(ws + 16777216);
    bf16* hBhi = (bf16*)(ws + 18874368);
    bf16* hBlo = (bf16*)(ws + 20971520);
    float* gq  = (float*)(ws + 23068672);              // [B][1536] f32

    const size_t s0_o = 0, s2_o = 1048576;
    const size_t q1_o = 2097152, k1_o = 2359296, v1_o = 2621440;
    const size_t q3_o = 2883584, k3_o = 3145728, v3_o = 3407872;

    CvtArgs ca;
    ca.src[0] = s0_W; ca.src[1] = s2_W;
    ca.src[2] = m1_Wq; ca.src[3] = m1_Wk; ca.src[4] = m1_Wv;
    ca.src[5] = m3_Wq; ca.src[6] = m3_Wk; ca.src[7] = m3_Wv;
    k_cvt<<<3584, 256, 0, stream>>>(ca, (unsigned short*)whi, (unsigned short*)wlo);

    k_h0<<<1024, 256, 0, stream>>>(V, t, ip_w, ip_b, (unsigned short*)hAhi, (unsigned short*)hAlo);

    // layer 0: sLSTM (i = W rows 0-511, g = rows 1024-1535, o = rows 1536-2047)
    k_gemm<<<384, 512, 0, stream>>>(hAhi, hAlo,
        whi + s0_o, whi + s0_o + 524288, whi + s0_o + 786432,
        wlo + s0_o, wlo + s0_o + 524288, wlo + s0_o + 786432,
        s0_b, s0_b + 1024, s0_b + 1536, gq);
    k_slstm_act<<<1024, 256, 0, stream>>>(gq, (unsigned short*)hBhi, (unsigned short*)hBlo);
    // layer 1: mLSTM (fused q|k|v)
    k_gemm<<<384, 512, 0, stream>>>(hBhi, hBlo,
        whi + q1_o, whi + k1_o, whi + v1_o,
        wlo + q1_o, wlo + k1_o, wlo + v1_o,
        m1_bq, m1_bk, m1_bv, gq);
    k_mlstm<<<BATCH, 512, 0, stream>>>(gq, hBhi, hBlo, m1_igw, m1_igb, m1_lng, m1_lnb,
                                       (unsigned short*)hAhi, (unsigned short*)hAlo);
    // layer 2: sLSTM
    k_gemm<<<384, 512, 0, stream>>>(hAhi, hAlo,
        whi + s2_o, whi + s2_o + 524288, whi + s2_o + 786432,
        wlo + s2_o, wlo + s2_o + 524288, wlo + s2_o + 786432,
        s2_b, s2_b + 1024, s2_b + 1536, gq);
    k_slstm_act<<<1024, 256, 0, stream>>>(gq, (unsigned short*)hBhi, (unsigned short*)hBlo);
    // layer 3: mLSTM
    k_gemm<<<384, 512, 0, stream>>>(hBhi, hBlo,
        whi + q3_o, whi + k3_o, whi + v3_o,
        wlo + q3_o, wlo + k3_o, wlo + v3_o,
        m3_bq, m3_bk, m3_bv, gq);
    k_mlstm<<<BATCH, 512, 0, stream>>>(gq, hBhi, hBlo, m3_igw, m3_igb, m3_lng, m3_lnb,
                                       (unsigned short*)hAhi, (unsigned short*)hAlo);

    k_out<<<512, 256, 0, stream>>>(hAhi, hAlo, op_w, op_b, (float*)d_out);
}

// Round 5
// 158.205 us; speedup vs baseline: 2.6442x; 1.1723x over previous
//
#include <hip/hip_runtime.h>
#include <hip/hip_bf16.h>

#define HID 512
#define BATCH 2048

typedef __bf16 bf16x8 __attribute__((ext_vector_type(8)));
typedef float f32x4 __attribute__((ext_vector_type(4)));
typedef float f32x16 __attribute__((ext_vector_type(16)));
typedef __hip_bfloat16 bf16;

__device__ inline unsigned short f2bf(float x) {
    bf16 h = __float2bfloat16(x);
    return __builtin_bit_cast(unsigned short, h);
}

__device__ inline void gload16(const void* g, void* l) {
    __builtin_amdgcn_global_load_lds((const __attribute__((address_space(1))) void*)g,
                                     (__attribute__((address_space(3))) void*)l, 16, 0, 0);
}

// ---------------- weight fp32 -> hi/lo bf16 split (x4 vectorized) ----------------
struct CvtArgs { const float* src[8]; };

__global__ void k_cvt(CvtArgs a, unsigned short* __restrict__ hi, unsigned short* __restrict__ lo) {
    int idx4 = (blockIdx.x * blockDim.x + threadIdx.x) << 2;   // total 3,670,016
    int seg, off;
    if (idx4 < 2097152) { seg = idx4 >> 20; off = idx4 & 1048575; }
    else { int r = idx4 - 2097152; seg = 2 + (r >> 18); off = r & 262143; }
    f32x4 w = *(const f32x4*)(a.src[seg] + off);
    ushort4 h, l;
    h.x = f2bf(w[0]); h.y = f2bf(w[1]); h.z = f2bf(w[2]); h.w = f2bf(w[3]);
    l.x = f2bf(w[0] - __bfloat162float(__builtin_bit_cast(bf16, h.x)));
    l.y = f2bf(w[1] - __bfloat162float(__builtin_bit_cast(bf16, h.y)));
    l.z = f2bf(w[2] - __bfloat162float(__builtin_bit_cast(bf16, h.z)));
    l.w = f2bf(w[3] - __bfloat162float(__builtin_bit_cast(bf16, h.w)));
    *(ushort4*)(hi + idx4) = h;
    *(ushort4*)(lo + idx4) = l;
}

// ---------------- input projection: h = [V,t] @ ip_w.T + ip_b (x4) ----------------
__global__ void k_h0(const float* __restrict__ V, const float* __restrict__ t,
                     const float* __restrict__ ipw, const float* __restrict__ ipb,
                     unsigned short* __restrict__ hhi, unsigned short* __restrict__ hlo) {
    int idx = blockIdx.x * blockDim.x + threadIdx.x;   // B*HID/4
    int b = idx >> 7, j4 = (idx & 127) << 2;
    float vv = V[b], tt = t[b];
    f32x4 w0 = *(const f32x4*)(ipw + 2 * j4);
    f32x4 w1 = *(const f32x4*)(ipw + 2 * j4 + 4);
    f32x4 bb = *(const f32x4*)(ipb + j4);
    float x[4] = { w0[0] * vv + w0[1] * tt + bb[0], w0[2] * vv + w0[3] * tt + bb[1],
                   w1[0] * vv + w1[1] * tt + bb[2], w1[2] * vv + w1[3] * tt + bb[3] };
    ushort4 h, l;
    h.x = f2bf(x[0]); h.y = f2bf(x[1]); h.z = f2bf(x[2]); h.w = f2bf(x[3]);
    l.x = f2bf(x[0] - __bfloat162float(__builtin_bit_cast(bf16, h.x)));
    l.y = f2bf(x[1] - __bfloat162float(__builtin_bit_cast(bf16, h.y)));
    l.z = f2bf(x[2] - __bfloat162float(__builtin_bit_cast(bf16, h.z)));
    l.w = f2bf(x[3] - __bfloat162float(__builtin_bit_cast(bf16, h.w)));
    size_t o = (size_t)b * HID + j4;
    *(ushort4*)(hhi + o) = h;
    *(ushort4*)(hlo + o) = l;
}

// ---------------- split-bf16 GEMM as ext-K bf16 GEMM, split-K over 2 halves ----------------
// C_kh[2048][1536] = A'[2048][768ext-half] * W'[1536][768ext-half]^T   (no bias here)
// ext-K segs (512 each): A' = {Ahi, Alo, Ahi};  W' = {Wh, Wh, Wl}.
// Block tile 128x128, 4 waves, wave tile 64x64 = 2x2 frags of mfma_f32_32x32x16_bf16, BK=64.
__global__ __launch_bounds__(256, 2) void k_gemm(
    const bf16* __restrict__ Ahi, const bf16* __restrict__ Alo,
    const bf16* __restrict__ Wh0, const bf16* __restrict__ Wh1, const bf16* __restrict__ Wh2,
    const bf16* __restrict__ Wl0, const bf16* __restrict__ Wl1, const bf16* __restrict__ Wl2,
    float* __restrict__ C0, float* __restrict__ C1)
{
    // LDS buffer (32KB): A 16 chunks (i=0..3 rowblk, ks=0..3), then B 16 chunks.
    // Chunk = 1KB = one 32x16 fragment group: lane l <-> row (l&31), k [(ks*16)+(l>>5)*8, +8)
    __shared__ __align__(16) bf16 lds[2][16384];
    const int tid = threadIdx.x, w = tid >> 6, lane = tid & 63;

    // bijective XCD-chunked swizzle over 384 blocks (48 per XCD)
    const int bid = blockIdx.x;
    const int id2 = (bid & 7) * 48 + (bid >> 3);
    const int kh  = id2 >= 192;
    const int r   = id2 - 192 * kh;
    const int m0  = (r / 12) * 128;
    const int n0  = (r % 12) * 128;
    const int nseg = n0 >> 9, nloc = n0 & 511;
    const bf16* Wh = nseg == 0 ? Wh0 : (nseg == 1 ? Wh1 : Wh2);
    const bf16* Wl = nseg == 0 ? Wl0 : (nseg == 1 ? Wl1 : Wl2);
    const int kbase = kh * 768;                        // ext-K offset of this half

    // staging: wave w stages A chunks (i=w, ks=0..3) and B chunks (j=w, ks=0..3)
    const size_t arow = (size_t)(m0 + 32 * w + (lane & 31)) * HID + ((lane >> 5) << 3);
    const size_t brow = (size_t)(nloc + 32 * w + (lane & 31)) * HID + ((lane >> 5) << 3);

    auto STAGE = [&](int t, int bb) {
        const int kk  = kbase + (t << 6);
        const int seg = kk >> 9;
        const int kl  = kk & 511;
        const bf16* ab = (seg == 1) ? Alo : Ahi;
        const bf16* wb = (seg == 2) ? Wl : Wh;
        bf16* lb = &lds[bb][0];
#pragma unroll
        for (int ks = 0; ks < 4; ++ks) {
            gload16(ab + arow + kl + 16 * ks, lb + (((w << 2) + ks) << 9) + (lane << 3));
            gload16(wb + brow + kl + 16 * ks, lb + 8192 + (((w << 2) + ks) << 9) + (lane << 3));
        }
    };

    const int i0 = (w >> 1) << 1, j0 = (w & 1) << 1;   // wave's A/B row-block pairs
    f32x16 acc00 = {}, acc01 = {}, acc10 = {}, acc11 = {};

    STAGE(0, 0);
    __syncthreads();
    for (int t = 0; t < 12; ++t) {
        const int cur = t & 1;
        if (t < 11) STAGE(t + 1, cur ^ 1);
        const bf16* lb = &lds[cur][0];
#pragma unroll
        for (int ks = 0; ks < 4; ++ks) {
            bf16x8 a0 = *(const bf16x8*)(lb + (((i0 << 2) + ks) << 9) + (lane << 3));
            bf16x8 a1 = *(const bf16x8*)(lb + ((((i0 + 1) << 2) + ks) << 9) + (lane << 3));
            bf16x8 b0 = *(const bf16x8*)(lb + 8192 + (((j0 << 2) + ks) << 9) + (lane << 3));
            bf16x8 b1 = *(const bf16x8*)(lb + 8192 + ((((j0 + 1) << 2) + ks) << 9) + (lane << 3));
            acc00 = __builtin_amdgcn_mfma_f32_32x32x16_bf16(a0, b0, acc00, 0, 0, 0);
            acc01 = __builtin_amdgcn_mfma_f32_32x32x16_bf16(a0, b1, acc01, 0, 0, 0);
            acc10 = __builtin_amdgcn_mfma_f32_32x32x16_bf16(a1, b0, acc10, 0, 0, 0);
            acc11 = __builtin_amdgcn_mfma_f32_32x32x16_bf16(a1, b1, acc11, 0, 0, 0);
        }
        __syncthreads();
    }

    // epilogue: D layout col = lane&31, row = (r&3) + 8*(r>>2) + 4*(lane>>5)
    float* Cp = kh ? C1 : C0;
    const f32x16* accs[2][2] = { { &acc00, &acc01 }, { &acc10, &acc11 } };
#pragma unroll
    for (int fi = 0; fi < 2; ++fi)
#pragma unroll
        for (int fj = 0; fj < 2; ++fj) {
            const f32x16& a = *accs[fi][fj];
            const int col = n0 + ((w & 1) << 6) + (fj << 5) + (lane & 31);
            const int rbase = m0 + ((w >> 1) << 6) + (fi << 5) + ((lane >> 5) << 2);
#pragma unroll
            for (int rr = 0; rr < 16; ++rr) {
                int row = rbase + (rr & 3) + ((rr >> 2) << 3);
                Cp[(size_t)row * 1536 + col] = a[rr];
            }
        }
}

// ---------------- sLSTM activation: sum partials + bias, h = sigm(o)*tanh(exp(i)*tanh(g)) ----------------
__global__ void k_slstm_act(const float* __restrict__ g0, const float* __restrict__ g1,
                            const float* __restrict__ bp,
                            unsigned short* __restrict__ hhi, unsigned short* __restrict__ hlo) {
    int idx = blockIdx.x * blockDim.x + threadIdx.x;   // B*HID/4
    int b = idx >> 7, j4 = (idx & 127) << 2;
    const float* r0 = g0 + (size_t)b * 1536 + j4;
    const float* r1 = g1 + (size_t)b * 1536 + j4;
    f32x4 gi = *(const f32x4*)r0 + *(const f32x4*)r1 + *(const f32x4*)(bp + j4);
    f32x4 gg = *(const f32x4*)(r0 + 512) + *(const f32x4*)(r1 + 512) + *(const f32x4*)(bp + 1024 + j4);
    f32x4 go = *(const f32x4*)(r0 + 1024) + *(const f32x4*)(r1 + 1024) + *(const f32x4*)(bp + 1536 + j4);
    ushort4 h, l;
    float x[4];
#pragma unroll
    for (int u = 0; u < 4; ++u)
        x[u] = tanhf(expf(gi[u]) * tanhf(gg[u])) / (1.f + expf(-go[u]));
    h.x = f2bf(x[0]); h.y = f2bf(x[1]); h.z = f2bf(x[2]); h.w = f2bf(x[3]);
    l.x = f2bf(x[0] - __bfloat162float(__builtin_bit_cast(bf16, h.x)));
    l.y = f2bf(x[1] - __bfloat162float(__builtin_bit_cast(bf16, h.y)));
    l.z = f2bf(x[2] - __bfloat162float(__builtin_bit_cast(bf16, h.z)));
    l.w = f2bf(x[3] - __bfloat162float(__builtin_bit_cast(bf16, h.w)));
    size_t o = (size_t)b * HID + j4;
    *(ushort4*)(hhi + o) = h;
    *(ushort4*)(hlo + o) = l;
}

// ---------------- mLSTM head math + layernorm (+optional fused final projection) ----------------
__global__ __launch_bounds__(512) void k_mlstm(
    const float* __restrict__ g0, const float* __restrict__ g1,
    const float* __restrict__ bq, const float* __restrict__ bk, const float* __restrict__ bv,
    const bf16* __restrict__ hinh, const bf16* __restrict__ hinl,
    const float* __restrict__ igw, const float* __restrict__ igb,
    const float* __restrict__ lng, const float* __restrict__ lnb,
    unsigned short* __restrict__ outh, unsigned short* __restrict__ outl,
    const float* __restrict__ opw, const float* __restrict__ opb, float* __restrict__ out)
{
    int b = blockIdx.x;
    int tid = threadIdx.x, head = tid >> 6, lane = tid & 63;

    const bf16*  hh = hinh + (size_t)b * HID;
    const bf16*  hl = hinl + (size_t)b * HID;
    const float* wrow = igw + head * HID;
    float s = 0.f;
#pragma unroll
    for (int k = 0; k < 8; ++k) {
        int p = lane + 64 * k;
        s += wrow[p] * (__bfloat162float(hh[p]) + __bfloat162float(hl[p]));
    }
#pragma unroll
    for (int off = 32; off; off >>= 1) s += __shfl_xor(s, off);
    float ig = expf(s + igb[head]);

    const float* r0 = g0 + (size_t)b * 1536;
    const float* r1 = g1 + (size_t)b * 1536;
    float q  = r0[tid] + r1[tid] + bq[tid];
    float kk = r0[512 + tid] + r1[512 + tid] + bk[tid];
    float v  = r0[1024 + tid] + r1[1024 + tid] + bv[tid];
    float kq = kk * q, vq = v * q;
#pragma unroll
    for (int off = 32; off; off >>= 1) { kq += __shfl_xor(kq, off); vq += __shfl_xor(vq, off); }
    float den = ig * (vq + 1.0f) + 1e-6f;
    float hv  = v * (ig * kq) / den;

    __shared__ float red[16];
    __shared__ float red2[8];
    float s1 = hv, s2 = hv * hv;
#pragma unroll
    for (int off = 32; off; off >>= 1) { s1 += __shfl_xor(s1, off); s2 += __shfl_xor(s2, off); }
    if (lane == 0) { red[head] = s1; red[8 + head] = s2; }
    __syncthreads();
    float t1 = 0.f, t2 = 0.f;
#pragma unroll
    for (int h2 = 0; h2 < 8; ++h2) { t1 += red[h2]; t2 += red[8 + h2]; }
    float mu  = t1 * (1.f / 512.f);
    float var = t2 * (1.f / 512.f) - mu * mu;
    float o = (hv - mu) * rsqrtf(var + 1e-5f) * lng[tid] + lnb[tid];

    if (out) {   // fused final projection (layer 3)
        float po = o * opw[tid];
#pragma unroll
        for (int off = 32; off; off >>= 1) po += __shfl_xor(po, off);
        if (lane == 0) red2[head] = po;
        __syncthreads();
        if (tid == 0) {
            float tt = 0.f;
#pragma unroll
            for (int h2 = 0; h2 < 8; ++h2) tt += red2[h2];
            out[b] = tt + opb[0];
        }
    } else {
        unsigned short oh = f2bf(o);
        size_t p = (size_t)b * HID + tid;
        outh[p] = oh;
        outl[p] = f2bf(o - __bfloat162float(__builtin_bit_cast(bf16, oh)));
    }
}

extern "C" void kernel_launch(void* const* d_in, const int* in_sizes, int n_in,
                              void* d_out, int out_size, void* d_ws, size_t ws_size,
                              hipStream_t stream) {
    const float* V    = (const float*)d_in[0];
    const float* t    = (const float*)d_in[1];
    const float* ip_w = (const float*)d_in[2];
    const float* ip_b = (const float*)d_in[3];
    const float* op_w = (const float*)d_in[4];
    const float* op_b = (const float*)d_in[5];
    const float* s0_W = (const float*)d_in[6];
    const float* s0_b = (const float*)d_in[7];
    const float* s2_W = (const float*)d_in[9];
    const float* s2_b = (const float*)d_in[10];
    const float* m1_Wq = (const float*)d_in[12];
    const float* m1_Wk = (const float*)d_in[13];
    const float* m1_Wv = (const float*)d_in[14];
    const float* m1_bq = (const float*)d_in[15];
    const float* m1_bk = (const float*)d_in[16];
    const float* m1_bv = (const float*)d_in[17];
    const float* m1_igw = (const float*)d_in[18];
    const float* m1_igb = (const float*)d_in[19];
    const float* m1_lng = (const float*)d_in[22];
    const float* m1_lnb = (const float*)d_in[23];
    const float* m3_Wq = (const float*)d_in[24];
    const float* m3_Wk = (const float*)d_in[25];
    const float* m3_Wv = (const float*)d_in[26];
    const float* m3_bq = (const float*)d_in[27];
    const float* m3_bk = (const float*)d_in[28];
    const float* m3_bv = (const float*)d_in[29];
    const float* m3_igw = (const float*)d_in[30];
    const float* m3_igb = (const float*)d_in[31];
    const float* m3_lng = (const float*)d_in[34];
    const float* m3_lnb = (const float*)d_in[35];

    char* ws = (char*)d_ws;
    bf16* whi  = (bf16*)ws;                            // 3,670,016 elems
    bf16* wlo  = (bf16*)(ws + 7340032);
    bf16* hAhi = (bf16*)(ws + 14680064);               // [B][HID] each 2 MB
    bf16* hAlo = (bf16*)(ws + 16777216);
    bf16* hBhi = (bf16*)(ws + 18874368);
    bf16* hBlo = (bf16*)(ws + 20971520);
    float* gq0 = (float*)(ws + 23068672);              // [B][1536] f32 partial (khalf 0)
    float* gq1 = (float*)(ws + 23068672 + 12582912);   // [B][1536] f32 partial (khalf 1)

    const size_t s0_o = 0, s2_o = 1048576;
    const size_t q1_o = 2097152, k1_o = 2359296, v1_o = 2621440;
    const size_t q3_o = 2883584, k3_o = 3145728, v3_o = 3407872;

    CvtArgs ca;
    ca.src[0] = s0_W; ca.src[1] = s2_W;
    ca.src[2] = m1_Wq; ca.src[3] = m1_Wk; ca.src[4] = m1_Wv;
    ca.src[5] = m3_Wq; ca.src[6] = m3_Wk; ca.src[7] = m3_Wv;
    k_cvt<<<3584, 256, 0, stream>>>(ca, (unsigned short*)whi, (unsigned short*)wlo);

    k_h0<<<1024, 256, 0, stream>>>(V, t, ip_w, ip_b, (unsigned short*)hAhi, (unsigned short*)hAlo);

    // layer 0: sLSTM (i = W rows 0-511, g = rows 1024-1535, o = rows 1536-2047)
    k_gemm<<<384, 256, 0, stream>>>(hAhi, hAlo,
        whi + s0_o, whi + s0_o + 524288, whi + s0_o + 786432,
        wlo + s0_o, wlo + s0_o + 524288, wlo + s0_o + 786432, gq0, gq1);
    k_slstm_act<<<1024, 256, 0, stream>>>(gq0, gq1, s0_b, (unsigned short*)hBhi, (unsigned short*)hBlo);
    // layer 1: mLSTM (fused q|k|v)
    k_gemm<<<384, 256, 0, stream>>>(hBhi, hBlo,
        whi + q1_o, whi + k1_o, whi + v1_o,
        wlo + q1_o, wlo + k1_o, wlo + v1_o, gq0, gq1);
    k_mlstm<<<BATCH, 512, 0, stream>>>(gq0, gq1, m1_bq, m1_bk, m1_bv, hBhi, hBlo,
                                       m1_igw, m1_igb, m1_lng, m1_lnb,
                                       (unsigned short*)hAhi, (unsigned short*)hAlo,
                                       nullptr, nullptr, nullptr);
    // layer 2: sLSTM
    k_gemm<<<384, 256, 0, stream>>>(hAhi, hAlo,
        whi + s2_o, whi + s2_o + 524288, whi + s2_o + 786432,
        wlo + s2_o, wlo + s2_o + 524288, wlo + s2_o + 786432, gq0, gq1);
    k_slstm_act<<<1024, 256, 0, stream>>>(gq0, gq1, s2_b, (unsigned short*)hBhi, (unsigned short*)hBlo);
    // layer 3: mLSTM + fused output projection
    k_gemm<<<384, 256, 0, stream>>>(hBhi, hBlo,
        whi + q3_o, whi + k3_o, whi + v3_o,
        wlo + q3_o, wlo + k3_o, wlo + v3_o, gq0, gq1);
    k_mlstm<<<BATCH, 512, 0, stream>>>(gq0, gq1, m3_bq, m3_bk, m3_bv, hBhi, hBlo,
                                       m3_igw, m3_igb, m3_lng, m3_lnb,
                                       nullptr, nullptr,
                                       op_w, op_b, (float*)d_out);
}

// Round 6
// 131.618 us; speedup vs baseline: 3.1783x; 1.2020x over previous
//
#include <hip/hip_runtime.h>
#include <hip/hip_bf16.h>

#define HID 512
#define BATCH 2048

typedef __bf16 bf16x8 __attribute__((ext_vector_type(8)));
typedef float f32x4 __attribute__((ext_vector_type(4)));
typedef float f32x16 __attribute__((ext_vector_type(16)));
typedef __hip_bfloat16 bf16;

__device__ inline unsigned short f2bf(float x) {
    bf16 h = __float2bfloat16(x);
    return __builtin_bit_cast(unsigned short, h);
}

__device__ inline void gload16(const void* g, void* l) {
    __builtin_amdgcn_global_load_lds((const __attribute__((address_space(1))) void*)g,
                                     (__attribute__((address_space(3))) void*)l, 16, 0, 0);
}

// ---------------- merged: weight fp32 -> hi/lo bf16 split  +  input projection ----------------
struct CvtArgs { const float* src[8]; };

__global__ void k_prep(CvtArgs a, unsigned short* __restrict__ hi, unsigned short* __restrict__ lo,
                       const float* __restrict__ V, const float* __restrict__ t,
                       const float* __restrict__ ipw, const float* __restrict__ ipb,
                       unsigned short* __restrict__ hhi, unsigned short* __restrict__ hlo) {
    const int bid = blockIdx.x;
    if (bid < 3584) {   // cvt part: 3,670,016 elems / 4
        int idx4 = (bid * 256 + threadIdx.x) << 2;
        int seg, off;
        if (idx4 < 2097152) { seg = idx4 >> 20; off = idx4 & 1048575; }
        else { int r = idx4 - 2097152; seg = 2 + (r >> 18); off = r & 262143; }
        f32x4 w = *(const f32x4*)(a.src[seg] + off);
        ushort4 h, l;
        h.x = f2bf(w[0]); h.y = f2bf(w[1]); h.z = f2bf(w[2]); h.w = f2bf(w[3]);
        l.x = f2bf(w[0] - __bfloat162float(__builtin_bit_cast(bf16, h.x)));
        l.y = f2bf(w[1] - __bfloat162float(__builtin_bit_cast(bf16, h.y)));
        l.z = f2bf(w[2] - __bfloat162float(__builtin_bit_cast(bf16, h.z)));
        l.w = f2bf(w[3] - __bfloat162float(__builtin_bit_cast(bf16, h.w)));
        *(ushort4*)(hi + idx4) = h;
        *(ushort4*)(lo + idx4) = l;
    } else {            // h0 part: B*HID/4 elems
        int idx = (bid - 3584) * 256 + threadIdx.x;
        int b = idx >> 7, j4 = (idx & 127) << 2;
        float vv = V[b], tt = t[b];
        f32x4 w0 = *(const f32x4*)(ipw + 2 * j4);
        f32x4 w1 = *(const f32x4*)(ipw + 2 * j4 + 4);
        f32x4 bb = *(const f32x4*)(ipb + j4);
        float x[4] = { w0[0] * vv + w0[1] * tt + bb[0], w0[2] * vv + w0[3] * tt + bb[1],
                       w1[0] * vv + w1[1] * tt + bb[2], w1[2] * vv + w1[3] * tt + bb[3] };
        ushort4 h, l;
        h.x = f2bf(x[0]); h.y = f2bf(x[1]); h.z = f2bf(x[2]); h.w = f2bf(x[3]);
        l.x = f2bf(x[0] - __bfloat162float(__builtin_bit_cast(bf16, h.x)));
        l.y = f2bf(x[1] - __bfloat162float(__builtin_bit_cast(bf16, h.y)));
        l.z = f2bf(x[2] - __bfloat162float(__builtin_bit_cast(bf16, h.z)));
        l.w = f2bf(x[3] - __bfloat162float(__builtin_bit_cast(bf16, h.w)));
        size_t o = (size_t)b * HID + j4;
        *(ushort4*)(hhi + o) = h;
        *(ushort4*)(hlo + o) = l;
    }
}

// ---------------- native-K split-bf16 GEMM, split-K over 2 halves ----------------
// C_kh[2048][1536] = Ah*Wh + Al*Wh + Ah*Wl over native K-half (256), no bias.
// Block 128x128, 4 waves, wave tile 64x64 = 2x2 frags of mfma_f32_32x32x16_bf16, BK=32.
// LDS buffer (32KB) = 32 chunks of 1KB; chunk c: matrix m=c>>3 (0=Ah,1=Al,2=Wh,3=Wl),
// rowblock rb=(c>>1)&3, ks=c&1. Chunk: lane l <-> row (l&31), k = 16*ks + 8*(l>>5) .. +8.
__global__ __launch_bounds__(256, 2) void k_gemm(
    const bf16* __restrict__ Ahi, const bf16* __restrict__ Alo,
    const bf16* __restrict__ Wh0, const bf16* __restrict__ Wh1, const bf16* __restrict__ Wh2,
    const bf16* __restrict__ Wl0, const bf16* __restrict__ Wl1, const bf16* __restrict__ Wl2,
    float* __restrict__ C0, float* __restrict__ C1)
{
    __shared__ __align__(16) bf16 lds[2][16384];
    const int tid = threadIdx.x, w = tid >> 6, lane = tid & 63;

    // bijective XCD-chunked swizzle over 384 blocks (48 per XCD)
    const int bid = blockIdx.x;
    const int id2 = (bid & 7) * 48 + (bid >> 3);
    const int kh  = id2 >= 192;
    const int r   = id2 - 192 * kh;
    const int m0  = (r / 12) * 128;
    const int n0  = (r % 12) * 128;
    const int nseg = n0 >> 9, nloc = n0 & 511;
    const bf16* Wh = nseg == 0 ? Wh0 : (nseg == 1 ? Wh1 : Wh2);
    const bf16* Wl = nseg == 0 ? Wl0 : (nseg == 1 ? Wl1 : Wl2);
    const int kbase = kh * 256;                        // native-K offset of this half

    // wave w stages matrix w (0=Ah, 1=Al, 2=Wh, 3=Wl): 8 chunks (rb 0..3 x ks 0..1)
    const bf16* msrc = (w == 0) ? Ahi : (w == 1) ? Alo : (w == 2) ? Wh : Wl;
    const int rowbase = (w < 2) ? m0 : nloc;
    const size_t srow = (size_t)(rowbase + (lane & 31)) * HID + kbase + ((lane >> 5) << 3);
    bf16* const ldst = &lds[0][0] + (w << 12) + (lane << 3);   // chunk (8w+p) at (8w+p)*512

    auto STAGE = [&](int t, int bb) {
        const size_t kq = srow + (t << 5);
        bf16* db = ldst + bb * 16384;
#pragma unroll
        for (int p = 0; p < 8; ++p)
            gload16(msrc + kq + (size_t)((p >> 1) << 5) * HID + ((p & 1) << 4), db + (p << 9));
    };

    const int wm = w >> 1, wn = w & 1;
    f32x16 acc00 = {}, acc01 = {}, acc10 = {}, acc11 = {};

    STAGE(0, 0);
    __syncthreads();
    for (int t = 0; t < 8; ++t) {
        const int cur = t & 1;
        if (t < 7) STAGE(t + 1, cur ^ 1);
        const bf16* lb = &lds[cur][0];
#pragma unroll
        for (int ks = 0; ks < 2; ++ks) {
            bf16x8 ah0 = *(const bf16x8*)(lb + ((( (2*wm  ) << 1) + ks) << 9) + (lane << 3));
            bf16x8 ah1 = *(const bf16x8*)(lb + ((( (2*wm+1) << 1) + ks) << 9) + (lane << 3));
            bf16x8 al0 = *(const bf16x8*)(lb + ((8 + ((2*wm  ) << 1) + ks) << 9) + (lane << 3));
            bf16x8 al1 = *(const bf16x8*)(lb + ((8 + ((2*wm+1) << 1) + ks) << 9) + (lane << 3));
            bf16x8 wh0 = *(const bf16x8*)(lb + ((16 + ((2*wn  ) << 1) + ks) << 9) + (lane << 3));
            bf16x8 wh1 = *(const bf16x8*)(lb + ((16 + ((2*wn+1) << 1) + ks) << 9) + (lane << 3));
            bf16x8 wl0 = *(const bf16x8*)(lb + ((24 + ((2*wn  ) << 1) + ks) << 9) + (lane << 3));
            bf16x8 wl1 = *(const bf16x8*)(lb + ((24 + ((2*wn+1) << 1) + ks) << 9) + (lane << 3));
            acc00 = __builtin_amdgcn_mfma_f32_32x32x16_bf16(ah0, wh0, acc00, 0, 0, 0);
            acc01 = __builtin_amdgcn_mfma_f32_32x32x16_bf16(ah0, wh1, acc01, 0, 0, 0);
            acc10 = __builtin_amdgcn_mfma_f32_32x32x16_bf16(ah1, wh0, acc10, 0, 0, 0);
            acc11 = __builtin_amdgcn_mfma_f32_32x32x16_bf16(ah1, wh1, acc11, 0, 0, 0);
            acc00 = __builtin_amdgcn_mfma_f32_32x32x16_bf16(al0, wh0, acc00, 0, 0, 0);
            acc01 = __builtin_amdgcn_mfma_f32_32x32x16_bf16(al0, wh1, acc01, 0, 0, 0);
            acc10 = __builtin_amdgcn_mfma_f32_32x32x16_bf16(al1, wh0, acc10, 0, 0, 0);
            acc11 = __builtin_amdgcn_mfma_f32_32x32x16_bf16(al1, wh1, acc11, 0, 0, 0);
            acc00 = __builtin_amdgcn_mfma_f32_32x32x16_bf16(ah0, wl0, acc00, 0, 0, 0);
            acc01 = __builtin_amdgcn_mfma_f32_32x32x16_bf16(ah0, wl1, acc01, 0, 0, 0);
            acc10 = __builtin_amdgcn_mfma_f32_32x32x16_bf16(ah1, wl0, acc10, 0, 0, 0);
            acc11 = __builtin_amdgcn_mfma_f32_32x32x16_bf16(ah1, wl1, acc11, 0, 0, 0);
        }
        __syncthreads();
    }

    // epilogue: D layout col = lane&31, row = (rr&3) + 8*(rr>>2) + 4*(lane>>5)
    float* Cp = kh ? C1 : C0;
    const f32x16* accs[2][2] = { { &acc00, &acc01 }, { &acc10, &acc11 } };
#pragma unroll
    for (int fi = 0; fi < 2; ++fi)
#pragma unroll
        for (int fj = 0; fj < 2; ++fj) {
            const f32x16& a = *accs[fi][fj];
            const int col = n0 + ((2 * wn + fj) << 5) + (lane & 31);
            const int rbase = m0 + ((2 * wm + fi) << 5) + ((lane >> 5) << 2);
#pragma unroll
            for (int rr = 0; rr < 16; ++rr) {
                int row = rbase + (rr & 3) + ((rr >> 2) << 3);
                Cp[(size_t)row * 1536 + col] = a[rr];
            }
        }
}

// ---------------- sLSTM activation: sum partials + bias, h = sigm(o)*tanh(exp(i)*tanh(g)) ----------------
__global__ void k_slstm_act(const float* __restrict__ g0, const float* __restrict__ g1,
                            const float* __restrict__ bp,
                            unsigned short* __restrict__ hhi, unsigned short* __restrict__ hlo) {
    int idx = blockIdx.x * blockDim.x + threadIdx.x;   // B*HID/4
    int b = idx >> 7, j4 = (idx & 127) << 2;
    const float* r0 = g0 + (size_t)b * 1536 + j4;
    const float* r1 = g1 + (size_t)b * 1536 + j4;
    f32x4 gi = *(const f32x4*)r0 + *(const f32x4*)r1 + *(const f32x4*)(bp + j4);
    f32x4 gg = *(const f32x4*)(r0 + 512) + *(const f32x4*)(r1 + 512) + *(const f32x4*)(bp + 1024 + j4);
    f32x4 go = *(const f32x4*)(r0 + 1024) + *(const f32x4*)(r1 + 1024) + *(const f32x4*)(bp + 1536 + j4);
    ushort4 h, l;
    float x[4];
#pragma unroll
    for (int u = 0; u < 4; ++u)
        x[u] = tanhf(expf(gi[u]) * tanhf(gg[u])) / (1.f + expf(-go[u]));
    h.x = f2bf(x[0]); h.y = f2bf(x[1]); h.z = f2bf(x[2]); h.w = f2bf(x[3]);
    l.x = f2bf(x[0] - __bfloat162float(__builtin_bit_cast(bf16, h.x)));
    l.y = f2bf(x[1] - __bfloat162float(__builtin_bit_cast(bf16, h.y)));
    l.z = f2bf(x[2] - __bfloat162float(__builtin_bit_cast(bf16, h.z)));
    l.w = f2bf(x[3] - __bfloat162float(__builtin_bit_cast(bf16, h.w)));
    size_t o = (size_t)b * HID + j4;
    *(ushort4*)(hhi + o) = h;
    *(ushort4*)(hlo + o) = l;
}

// ---------------- mLSTM head math + layernorm (+optional fused final projection) ----------------
__global__ __launch_bounds__(512) void k_mlstm(
    const float* __restrict__ g0, const float* __restrict__ g1,
    const float* __restrict__ bq, const float* __restrict__ bk, const float* __restrict__ bv,
    const bf16* __restrict__ hinh, const bf16* __restrict__ hinl,
    const float* __restrict__ igw, const float* __restrict__ igb,
    const float* __restrict__ lng, const float* __restrict__ lnb,
    unsigned short* __restrict__ outh, unsigned short* __restrict__ outl,
    const float* __restrict__ opw, const float* __restrict__ opb, float* __restrict__ out)
{
    int b = blockIdx.x;
    int tid = threadIdx.x, head = tid >> 6, lane = tid & 63;

    const bf16*  hh = hinh + (size_t)b * HID;
    const bf16*  hl = hinl + (size_t)b * HID;
    const float* wrow = igw + head * HID;
    float s = 0.f;
#pragma unroll
    for (int k = 0; k < 8; ++k) {
        int p = lane + 64 * k;
        s += wrow[p] * (__bfloat162float(hh[p]) + __bfloat162float(hl[p]));
    }
#pragma unroll
    for (int off = 32; off; off >>= 1) s += __shfl_xor(s, off);
    float ig = expf(s + igb[head]);

    const float* r0 = g0 + (size_t)b * 1536;
    const float* r1 = g1 + (size_t)b * 1536;
    float q  = r0[tid] + r1[tid] + bq[tid];
    float kk = r0[512 + tid] + r1[512 + tid] + bk[tid];
    float v  = r0[1024 + tid] + r1[1024 + tid] + bv[tid];
    float kq = kk * q, vq = v * q;
#pragma unroll
    for (int off = 32; off; off >>= 1) { kq += __shfl_xor(kq, off); vq += __shfl_xor(vq, off); }
    float den = ig * (vq + 1.0f) + 1e-6f;
    float hv  = v * (ig * kq) / den;

    __shared__ float red[16];
    __shared__ float red2[8];
    float s1 = hv, s2 = hv * hv;
#pragma unroll
    for (int off = 32; off; off >>= 1) { s1 += __shfl_xor(s1, off); s2 += __shfl_xor(s2, off); }
    if (lane == 0) { red[head] = s1; red[8 + head] = s2; }
    __syncthreads();
    float t1 = 0.f, t2 = 0.f;
#pragma unroll
    for (int h2 = 0; h2 < 8; ++h2) { t1 += red[h2]; t2 += red[8 + h2]; }
    float mu  = t1 * (1.f / 512.f);
    float var = t2 * (1.f / 512.f) - mu * mu;
    float o = (hv - mu) * rsqrtf(var + 1e-5f) * lng[tid] + lnb[tid];

    if (out) {   // fused final projection (layer 3)
        float po = o * opw[tid];
#pragma unroll
        for (int off = 32; off; off >>= 1) po += __shfl_xor(po, off);
        if (lane == 0) red2[head] = po;
        __syncthreads();
        if (tid == 0) {
            float tt = 0.f;
#pragma unroll
            for (int h2 = 0; h2 < 8; ++h2) tt += red2[h2];
            out[b] = tt + opb[0];
        }
    } else {
        unsigned short oh = f2bf(o);
        size_t p = (size_t)b * HID + tid;
        outh[p] = oh;
        outl[p] = f2bf(o - __bfloat162float(__builtin_bit_cast(bf16, oh)));
    }
}

extern "C" void kernel_launch(void* const* d_in, const int* in_sizes, int n_in,
                              void* d_out, int out_size, void* d_ws, size_t ws_size,
                              hipStream_t stream) {
    const float* V    = (const float*)d_in[0];
    const float* t    = (const float*)d_in[1];
    const float* ip_w = (const float*)d_in[2];
    const float* ip_b = (const float*)d_in[3];
    const float* op_w = (const float*)d_in[4];
    const float* op_b = (const float*)d_in[5];
    const float* s0_W = (const float*)d_in[6];
    const float* s0_b = (const float*)d_in[7];
    const float* s2_W = (const float*)d_in[9];
    const float* s2_b = (const float*)d_in[10];
    const float* m1_Wq = (const float*)d_in[12];
    const float* m1_Wk = (const float*)d_in[13];
    const float* m1_Wv = (const float*)d_in[14];
    const float* m1_bq = (const float*)d_in[15];
    const float* m1_bk = (const float*)d_in[16];
    const float* m1_bv = (const float*)d_in[17];
    const float* m1_igw = (const float*)d_in[18];
    const float* m1_igb = (const float*)d_in[19];
    const float* m1_lng = (const float*)d_in[22];
    const float* m1_lnb = (const float*)d_in[23];
    const float* m3_Wq = (const float*)d_in[24];
    const float* m3_Wk = (const float*)d_in[25];
    const float* m3_Wv = (const float*)d_in[26];
    const float* m3_bq = (const float*)d_in[27];
    const float* m3_bk = (const float*)d_in[28];
    const float* m3_bv = (const float*)d_in[29];
    const float* m3_igw = (const float*)d_in[30];
    const float* m3_igb = (const float*)d_in[31];
    const float* m3_lng = (const float*)d_in[34];
    const float* m3_lnb = (const float*)d_in[35];

    char* ws = (char*)d_ws;
    bf16* whi  = (bf16*)ws;                            // 3,670,016 elems
    bf16* wlo  = (bf16*)(ws + 7340032);
    bf16* hAhi = (bf16*)(ws + 14680064);               // [B][HID] each 2 MB
    bf16* hAlo = (bf16*)(ws + 16777216);
    bf16* hBhi = (bf16*)(ws + 18874368);
    bf16* hBlo = (bf16*)(ws + 20971520);
    float* gq0 = (float*)(ws + 23068672);              // [B][1536] f32 partial (khalf 0)
    float* gq1 = (float*)(ws + 23068672 + 12582912);   // [B][1536] f32 partial (khalf 1)

    const size_t s0_o = 0, s2_o = 1048576;
    const size_t q1_o = 2097152, k1_o = 2359296, v1_o = 2621440;
    const size_t q3_o = 2883584, k3_o = 3145728, v3_o = 3407872;

    CvtArgs ca;
    ca.src[0] = s0_W; ca.src[1] = s2_W;
    ca.src[2] = m1_Wq; ca.src[3] = m1_Wk; ca.src[4] = m1_Wv;
    ca.src[5] = m3_Wq; ca.src[6] = m3_Wk; ca.src[7] = m3_Wv;
    k_prep<<<4608, 256, 0, stream>>>(ca, (unsigned short*)whi, (unsigned short*)wlo,
                                     V, t, ip_w, ip_b,
                                     (unsigned short*)hAhi, (unsigned short*)hAlo);

    // layer 0: sLSTM (i = W rows 0-511, g = rows 1024-1535, o = rows 1536-2047)
    k_gemm<<<384, 256, 0, stream>>>(hAhi, hAlo,
        whi + s0_o, whi + s0_o + 524288, whi + s0_o + 786432,
        wlo + s0_o, wlo + s0_o + 524288, wlo + s0_o + 786432, gq0, gq1);
    k_slstm_act<<<1024, 256, 0, stream>>>(gq0, gq1, s0_b, (unsigned short*)hBhi, (unsigned short*)hBlo);
    // layer 1: mLSTM (fused q|k|v)
    k_gemm<<<384, 256, 0, stream>>>(hBhi, hBlo,
        whi + q1_o, whi + k1_o, whi + v1_o,
        wlo + q1_o, wlo + k1_o, wlo + v1_o, gq0, gq1);
    k_mlstm<<<BATCH, 512, 0, stream>>>(gq0, gq1, m1_bq, m1_bk, m1_bv, hBhi, hBlo,
                                       m1_igw, m1_igb, m1_lng, m1_lnb,
                                       (unsigned short*)hAhi, (unsigned short*)hAlo,
                                       nullptr, nullptr, nullptr);
    // layer 2: sLSTM
    k_gemm<<<384, 256, 0, stream>>>(hAhi, hAlo,
        whi + s2_o, whi + s2_o + 524288, whi + s2_o + 786432,
        wlo + s2_o, wlo + s2_o + 524288, wlo + s2_o + 786432, gq0, gq1);
    k_slstm_act<<<1024, 256, 0, stream>>>(gq0, gq1, s2_b, (unsigned short*)hBhi, (unsigned short*)hBlo);
    // layer 3: mLSTM + fused output projection
    k_gemm<<<384, 256, 0, stream>>>(hBhi, hBlo,
        whi + q3_o, whi + k3_o, whi + v3_o,
        wlo + q3_o, wlo + k3_o, wlo + v3_o, gq0, gq1);
    k_mlstm<<<BATCH, 512, 0, stream>>>(gq0, gq1, m3_bq, m3_bk, m3_bv, hBhi, hBlo,
                                       m3_igw, m3_igb, m3_lng, m3_lnb,
                                       nullptr, nullptr,
                                       op_w, op_b, (float*)d_out);
}